// Round 11
// baseline (79.563 us; speedup 1.0000x reference)
//
#include <hip/hip_runtime.h>

// Bahdanau additive attention scores:
//   enc = keys @ W1 + b1          [B,S,U]
//   dec = query @ W2 + b2         [B,T,U]
//   score[b,t,s] = bV + sum_u tanh(enc[b,s,u] + dec[b,t,u]) * V[u]
//
// B=4, T=128, S=512, D=128, U=128. All fp32.
//
// R11: V via scalar loads. R6 (direct LDS indexing) was NULL -> K2 is
//     DS-pipe-bound (4x ds_read_b128 = 64B/k4/thread ~= 5.1us), not
//     VALU/flat-bound. V is wave-uniform -> read it straight from global
//     with uniform addressing so the compiler emits s_load_dwordx4 on the
//     scalar pipe (SMEM, sL1-cached): DS traffic 64->48 B/k4 (-25%).
//     Math unchanged: tanh(x) = 1 - 2/(exp2(d)*exp2(e)+1), exp in K1.

#define B_ 4
#define T_ 128
#define S_ 512
#define D_ 128
#define U_ 128

// 2/ln(2)
#define SCALE2 2.88539008177792681f

// ---------------------------------------------------------------------------
// Kernel 1: encE[r][u] = exp2( SCALE2*(sum_k x[r][k]*W[k][u] + bias[u]) )
// 2048 enc rows (keys) + 512 dec rows (query) = 2560 rows.
// Block = 256 threads handles 8 rows x 128 u; each thread: 4 rows, 1 u.
// blocks 0..255 -> enc (keys/W1/b1), blocks 256..319 -> dec (query/W2/b2).
// ---------------------------------------------------------------------------
__global__ __launch_bounds__(256) void precompute_kernel(
    const float* __restrict__ query, const float* __restrict__ keys,
    const float* __restrict__ W1, const float* __restrict__ b1,
    const float* __restrict__ W2, const float* __restrict__ b2,
    float* __restrict__ encE, float* __restrict__ decE)
{
    __shared__ float xs[8][132];   // 8 rows x 128 k, padded stride

    const int blk = blockIdx.x;
    const float* src;
    const float* W;
    const float* bias;
    float* dst;
    if (blk < 256) {
        int row0 = blk * 8;
        src = keys + row0 * D_;
        W = W1; bias = b1;
        dst = encE + row0 * U_;
    } else {
        int row0 = (blk - 256) * 8;
        src = query + row0 * D_;
        W = W2; bias = b2;
        dst = decE + row0 * U_;
    }

    const int tid = threadIdx.x;

    // stage 8x128 floats = 256 float4, one per thread, fully coalesced
    {
        int r = tid >> 5;          // /32 float4-per-row
        int c4 = tid & 31;
        float4 v = reinterpret_cast<const float4*>(src)[tid];
        xs[r][c4 * 4 + 0] = v.x;
        xs[r][c4 * 4 + 1] = v.y;
        xs[r][c4 * 4 + 2] = v.z;
        xs[r][c4 * 4 + 3] = v.w;
    }
    __syncthreads();

    const int u = tid & 127;
    const int rh = (tid >> 7) * 4; // 0 or 4 -> rows rh..rh+3
    const float bb = bias[u];

    float acc0 = 0.f, acc1 = 0.f, acc2 = 0.f, acc3 = 0.f;
    #pragma unroll 4
    for (int k4 = 0; k4 < 32; ++k4) {
        const int k = k4 * 4;
        float w0 = W[(k + 0) * U_ + u];
        float w1 = W[(k + 1) * U_ + u];
        float w2 = W[(k + 2) * U_ + u];
        float w3 = W[(k + 3) * U_ + u];
        // direct __shared__ indexing -> ds_read, broadcast within wave
        acc0 += xs[rh + 0][k] * w0 + xs[rh + 0][k + 1] * w1 + xs[rh + 0][k + 2] * w2 + xs[rh + 0][k + 3] * w3;
        acc1 += xs[rh + 1][k] * w0 + xs[rh + 1][k + 1] * w1 + xs[rh + 1][k + 2] * w2 + xs[rh + 1][k + 3] * w3;
        acc2 += xs[rh + 2][k] * w0 + xs[rh + 2][k + 1] * w1 + xs[rh + 2][k + 2] * w2 + xs[rh + 2][k + 3] * w3;
        acc3 += xs[rh + 3][k] * w0 + xs[rh + 3][k + 1] * w1 + xs[rh + 3][k + 2] * w2 + xs[rh + 3][k + 3] * w3;
    }

    dst[(rh + 0) * U_ + u] = __builtin_amdgcn_exp2f(SCALE2 * (acc0 + bb));
    dst[(rh + 1) * U_ + u] = __builtin_amdgcn_exp2f(SCALE2 * (acc1 + bb));
    dst[(rh + 2) * U_ + u] = __builtin_amdgcn_exp2f(SCALE2 * (acc2 + bb));
    dst[(rh + 3) * U_ + u] = __builtin_amdgcn_exp2f(SCALE2 * (acc3 + bb));
}

// ---------------------------------------------------------------------------
// Kernel 2: fused score. Block = 256 threads handles a 16t x 32s tile for one b.
// Thread (tt = tid>>4, ss = tid&15) computes outputs (tt, ss) and (tt, ss+16).
// grid = (S/32, T/16, B) = (16, 8, 4) = 512 blocks, 2 blocks/CU, 2 waves/SIMD.
// score = (bV + sum(V)) - 2 * sum_u V[u] * rcp( E[s][u]*D[t][u] + 1 )
// V read via uniform scalar loads (s_load_dwordx4) -> off the DS pipe.
// ---------------------------------------------------------------------------
__global__ __launch_bounds__(256) void score_kernel(
    const float* __restrict__ encE, const float* __restrict__ decE,
    const float* __restrict__ V, const float* __restrict__ bV,
    float* __restrict__ out)
{
    __shared__ float4 se[32][33];  // enc-exp tile as float4[32 rows][32 quads +1 pad]
    __shared__ float4 sd[16][33];  // dec-exp tile
    __shared__ float sC;           // bV + sum(V)

    const int b  = blockIdx.z;
    const int t0 = blockIdx.y * 16;
    const int s0 = blockIdx.x * 32;
    const int tid = threadIdx.x;

    // stage enc tile: 32 rows x 32 quads = 1024 float4 -> 4/thread, coalesced
    {
        const float4* esrc = reinterpret_cast<const float4*>(encE + (b * S_ + s0) * U_);
        #pragma unroll
        for (int j = 0; j < 4; ++j) {
            int f = tid + j * 256;
            se[f >> 5][f & 31] = esrc[f];
        }
    }
    // stage dec tile: 16 rows x 32 quads = 512 float4 -> 2/thread
    {
        const float4* dsrc = reinterpret_cast<const float4*>(decE + (b * T_ + t0) * U_);
        #pragma unroll
        for (int j = 0; j < 2; ++j) {
            int f = tid + j * 256;
            sd[f >> 5][f & 31] = dsrc[f];
        }
    }
    // compute sC = bV + sum(V) in lanes 0..31 of wave 0 (no LDS staging of V)
    if (tid < 32) {
        float4 v = reinterpret_cast<const float4*>(V)[tid];
        float p = v.x + v.y + v.z + v.w;
        p += __shfl_xor(p, 1);
        p += __shfl_xor(p, 2);
        p += __shfl_xor(p, 4);
        p += __shfl_xor(p, 8);
        p += __shfl_xor(p, 16);
        if (tid == 0) sC = p + bV[0];
    }
    __syncthreads();

    const int tt = tid >> 4;
    const int ss = tid & 15;
    const float4* Vq = reinterpret_cast<const float4*>(V);  // uniform base

    // 2-way split accumulators: halves the serial FMA dependency chain.
    float accA0 = 0.f, accA1 = 0.f, accB0 = 0.f, accB1 = 0.f;
    #pragma unroll 4
    for (int k4 = 0; k4 < 32; ++k4) {
        // LDS: 3 ds_read_b128 per k4 (was 4)
        float4 d  = sd[tt][k4];
        float4 a  = se[ss][k4];
        float4 e2 = se[ss + 16][k4];
        // V: uniform address -> scalar pipe (s_load_dwordx4), zero DS slots
        float4 vv = Vq[k4];
        // r = 1/(E*D+1); tanh = 1-2r folded into epilogue via sC
        accA0 += vv.x * __builtin_amdgcn_rcpf(__builtin_fmaf(a.x,  d.x, 1.f));
        accA1 += vv.y * __builtin_amdgcn_rcpf(__builtin_fmaf(a.y,  d.y, 1.f));
        accA0 += vv.z * __builtin_amdgcn_rcpf(__builtin_fmaf(a.z,  d.z, 1.f));
        accA1 += vv.w * __builtin_amdgcn_rcpf(__builtin_fmaf(a.w,  d.w, 1.f));
        accB0 += vv.x * __builtin_amdgcn_rcpf(__builtin_fmaf(e2.x, d.x, 1.f));
        accB1 += vv.y * __builtin_amdgcn_rcpf(__builtin_fmaf(e2.y, d.y, 1.f));
        accB0 += vv.z * __builtin_amdgcn_rcpf(__builtin_fmaf(e2.z, d.z, 1.f));
        accB1 += vv.w * __builtin_amdgcn_rcpf(__builtin_fmaf(e2.w, d.w, 1.f));
    }

    const float C = sC;
    const int obase = (b * T_ + t0 + tt) * S_ + s0 + ss;
    out[obase]      = C - 2.f * (accA0 + accA1);
    out[obase + 16] = C - 2.f * (accB0 + accB1);
}

// ---------------------------------------------------------------------------
extern "C" void kernel_launch(void* const* d_in, const int* in_sizes, int n_in,
                              void* d_out, int out_size, void* d_ws, size_t ws_size,
                              hipStream_t stream)
{
    const float* query = (const float*)d_in[0];
    const float* keys  = (const float*)d_in[1];
    const float* W1    = (const float*)d_in[2];
    const float* b1    = (const float*)d_in[3];
    const float* W2    = (const float*)d_in[4];
    const float* b2    = (const float*)d_in[5];
    const float* V     = (const float*)d_in[6];
    const float* bV    = (const float*)d_in[7];
    float* out = (float*)d_out;

    float* encE = (float*)d_ws;                    // [B*S][U] = 2048*128 floats (1 MB)
    float* decE = encE + (B_ * S_ * U_);           // [B*T][U] = 512*128 floats (256 KB)

    precompute_kernel<<<dim3(320), dim3(256), 0, stream>>>(
        query, keys, W1, b1, W2, b2, encE, decE);

    score_kernel<<<dim3(S_ / 32, T_ / 16, B_), dim3(256), 0, stream>>>(
        encE, decE, V, bV, out);
}